// Round 17
// baseline (617.081 us; speedup 1.0000x reference)
//
#include <hip/hip_runtime.h>
#include <hip/hip_bf16.h>
#include <math.h>

#define B_ 4
#define L_ 2048
#define H_ 8
#define E_ 64
#define HE 512   // H_*E_ : float stride between consecutive seq positions

typedef short bf16x8 __attribute__((ext_vector_type(8)));
typedef float f32x4 __attribute__((ext_vector_type(4)));
typedef float f32x16 __attribute__((ext_vector_type(16)));
typedef unsigned short u16x4 __attribute__((ext_vector_type(4)));
typedef unsigned short u16x8 __attribute__((ext_vector_type(8)));

__device__ __forceinline__ unsigned short f2b(float f) {
  return __builtin_bit_cast(unsigned short, (__hip_bfloat16)f);
}
__device__ __forceinline__ unsigned cvtpk(float lo, float hi) {
  unsigned r;
  asm("v_cvt_pk_bf16_f32 %0, %1, %2" : "=v"(r) : "v"(lo), "v"(hi));
  return r;
}
// T12 pair-swap: verified ONLY with two distinct live values (PV path).
__device__ __forceinline__ void pl32swap(unsigned &a, unsigned &b) {
  asm volatile("v_permlane32_swap_b32 %0, %1" : "+v"(a), "+v"(b));
}

// ---------------- REAL kernel: exact R16 (passed, 54.6us) ----------------
__global__ __launch_bounds__(512, 1) void attn_fwd(
    const float* __restrict__ Q, const float* __restrict__ K,
    const float* __restrict__ V, const float* __restrict__ tau,
    float* __restrict__ O)
{
  const int f  = blockIdx.x + 16 * (blockIdx.y + 8 * blockIdx.z);
  const int u  = f >> 5, hb = f & 31;
  const int h  = hb & 7, b = hb >> 3;
  const int qt = (u < 8) ? u : 23 - u;

  const int tid  = threadIdx.x;
  const int wave = tid >> 6, lane = tid & 63;
  const int l31 = lane & 31, hi = lane >> 5;
  const int l7 = l31 & 7;
  const int half = wave >> 2, wv = wave & 3;

  __shared__ union {
    struct { unsigned short Kt[2][2][64 * 64];
             unsigned short Vt[2][2][64 * 64]; } kv;
    struct { float O[128][64]; float m[128]; float l[128]; } cmb;
  } sm;

  const float qscale = 0.125f * expf(tau[b]) * 1.44269504088896f;
  const int q0w = qt * 128 + wv * 32;
  const int myq = q0w + l31;
  const int dqd = 32 * wv + l31 - 64 * half;
  const bool skipw = (half == 1) && (wv < 2);

  const float* Qb = Q + (((size_t)b * L_ + myq) * H_ + h) * E_;
  bf16x8 qf[4];
  #pragma unroll
  for (int ks = 0; ks < 4; ++ks) {
    f32x4 a = *(const f32x4*)(Qb + ks * 16 + hi * 8);
    f32x4 c = *(const f32x4*)(Qb + ks * 16 + hi * 8 + 4);
    #pragma unroll
    for (int j = 0; j < 4; ++j) {
      qf[ks][j]     = (short)f2b(a[j] * qscale);
      qf[ks][4 + j] = (short)f2b(c[j] * qscale);
    }
  }

  float m_run = -INFINITY, l_run = 0.0f;
  f32x16 oacc[2];
  #pragma unroll
  for (int nd = 0; nd < 2; ++nd)
    #pragma unroll
    for (int r = 0; r < 16; ++r) oacc[nd][r] = 0.0f;

  const int hs = tid >> 8, st = tid & 255;
  const int krow = st >> 2, kcg = st & 3;
  const int vkv = (st & 15) * 4, vd = (st >> 4) * 4;
  const size_t bh = ((size_t)b * L_ * H_ + h) * E_;
  const float* Kp = K + bh + (size_t)(64 * hs + krow) * HE + kcg * 16;
  const float* Vp = V + bh + (size_t)(64 * hs + vkv) * HE + vd;
  const int kwo0 = krow * 64 + (((2 * kcg)     ^ (krow & 7)) << 3);
  const int kwo1 = krow * 64 + (((2 * kcg + 1) ^ (krow & 7)) << 3);

  const int nt = qt + 1;

  f32x4 kq[4], vq[4];
  #pragma unroll
  for (int i = 0; i < 4; ++i) kq[i] = *(const f32x4*)(Kp + 4 * i);
  #pragma unroll
  for (int i = 0; i < 4; ++i) vq[i] = *(const f32x4*)(Vp + (size_t)i * HE);
  {
    u16x8 w0, w1;
    #pragma unroll
    for (int j = 0; j < 4; ++j) {
      w0[j] = f2b(kq[0][j]); w0[4 + j] = f2b(kq[1][j]);
      w1[j] = f2b(kq[2][j]); w1[4 + j] = f2b(kq[3][j]);
    }
    *(u16x8*)(&sm.kv.Kt[hs][0][kwo0]) = w0;
    *(u16x8*)(&sm.kv.Kt[hs][0][kwo1]) = w1;
    #pragma unroll
    for (int jd = 0; jd < 4; ++jd) {
      const int row = vd + jd;
      u16x4 vw;
      #pragma unroll
      for (int i = 0; i < 4; ++i) vw[i] = f2b(vq[i][jd]);
      *(u16x4*)(&sm.kv.Vt[hs][0][row * 64 + (((vkv >> 3) ^ (row & 7)) << 3) + (vkv & 7)]) = vw;
    }
  }
  __syncthreads();
  int cur = 0;

  for (int t = 0; t < nt; ++t) {
    const bool havenext = (t + 1 < nt);
    if (havenext) {
      const float* Kn = Kp + (size_t)(t + 1) * 128 * HE;
      const float* Vn = Vp + (size_t)(t + 1) * 128 * HE;
      #pragma unroll
      for (int i = 0; i < 4; ++i) kq[i] = *(const f32x4*)(Kn + 4 * i);
      #pragma unroll
      for (int i = 0; i < 4; ++i) vq[i] = *(const f32x4*)(Vn + (size_t)i * HE);
    }

    if (!(skipw && t == nt - 1)) {
      const unsigned short* Kl = sm.kv.Kt[half][cur];
      const unsigned short* Vl = sm.kv.Vt[half][cur];

      f32x16 sacc[2];
      #pragma unroll
      for (int mt = 0; mt < 2; ++mt)
        #pragma unroll
        for (int r = 0; r < 16; ++r) sacc[mt][r] = 0.0f;
      __builtin_amdgcn_s_setprio(1);
      #pragma unroll
      for (int ks = 0; ks < 4; ++ks) {
        #pragma unroll
        for (int mt = 0; mt < 2; ++mt) {
          bf16x8 kf = *(const bf16x8*)(Kl + (32 * mt + l31) * 64 +
                                       (((2 * ks + hi) ^ l7) << 3));
          sacc[mt] = __builtin_amdgcn_mfma_f32_32x32x16_bf16(kf, qf[ks], sacc[mt], 0, 0, 0);
        }
      }
      __builtin_amdgcn_s_setprio(0);

      if (t == nt - 1) {
        #pragma unroll
        for (int mt = 0; mt < 2; ++mt)
          #pragma unroll
          for (int r = 0; r < 16; ++r) {
            const int kvl = 32 * mt + (r & 3) + 8 * (r >> 2) + 4 * hi;
            if (kvl > dqd) sacc[mt][r] = -3.0e38f;
          }
      }

      float p0 = sacc[0][0], p1 = sacc[0][1], p2 = sacc[0][2], p3 = sacc[0][3];
      #pragma unroll
      for (int mt = 0; mt < 2; ++mt)
        #pragma unroll
        for (int r = (mt == 0 ? 4 : 0); r < 16; r += 4) {
          p0 = fmaxf(p0, sacc[mt][r]);
          p1 = fmaxf(p1, sacc[mt][r + 1]);
          p2 = fmaxf(p2, sacc[mt][r + 2]);
          p3 = fmaxf(p3, sacc[mt][r + 3]);
        }
      float mx = fmaxf(fmaxf(p0, p1), fmaxf(p2, p3));
      mx = fmaxf(mx, __shfl_xor(mx, 32));

      if (!__all(mx - m_run <= 8.0f)) {
        const float mnew = fmaxf(m_run, mx);
        const float corr = exp2f(m_run - mnew);
        m_run = mnew;
        l_run *= corr;
        #pragma unroll
        for (int r = 0; r < 16; ++r) {
          const int qrow = (r & 3) + 8 * (r >> 2) + 4 * hi;
          const float cr = __shfl(corr, qrow);
          oacc[0][r] *= cr;
          oacc[1][r] *= cr;
        }
      }

      float s0 = 0.f, s1 = 0.f, s2 = 0.f, s3 = 0.f;
      #pragma unroll
      for (int mt = 0; mt < 2; ++mt)
        #pragma unroll
        for (int r = 0; r < 16; r += 4) {
          float e0 = exp2f(sacc[mt][r]     - m_run);
          float e1 = exp2f(sacc[mt][r + 1] - m_run);
          float e2 = exp2f(sacc[mt][r + 2] - m_run);
          float e3 = exp2f(sacc[mt][r + 3] - m_run);
          sacc[mt][r] = e0; sacc[mt][r + 1] = e1;
          sacc[mt][r + 2] = e2; sacc[mt][r + 3] = e3;
          s0 += e0; s1 += e1; s2 += e2; s3 += e3;
        }
      l_run += (s0 + s1) + (s2 + s3);

      unsigned pk[2][8];
      #pragma unroll
      for (int mt = 0; mt < 2; ++mt)
        #pragma unroll
        for (int i = 0; i < 8; ++i)
          pk[mt][i] = cvtpk(sacc[mt][2 * i], sacc[mt][2 * i + 1]);

      __builtin_amdgcn_s_setprio(1);
      #pragma unroll
      for (int ks = 0; ks < 4; ++ks) {
        const int c = ks & 1, mtx = ks >> 1;
        unsigned a  = pk[mtx][4 * c];
        unsigned y  = pk[mtx][4 * c + 2];
        unsigned a2 = pk[mtx][4 * c + 1];
        unsigned y2 = pk[mtx][4 * c + 3];
        pl32swap(a, y);
        pl32swap(a2, y2);
        union { unsigned w[4]; bf16x8 v; } pu;
        pu.w[0] = a; pu.w[1] = a2; pu.w[2] = y; pu.w[3] = y2;
        #pragma unroll
        for (int nd = 0; nd < 2; ++nd) {
          bf16x8 vf = *(const bf16x8*)(Vl + (32 * nd + l31) * 64 +
                                       (((2 * ks + hi) ^ l7) << 3));
          oacc[nd] = __builtin_amdgcn_mfma_f32_32x32x16_bf16(pu.v, vf, oacc[nd], 0, 0, 0);
        }
      }
      __builtin_amdgcn_s_setprio(0);
    }

    if (havenext) {
      const int nb = cur ^ 1;
      u16x8 w0, w1;
      #pragma unroll
      for (int j = 0; j < 4; ++j) {
        w0[j] = f2b(kq[0][j]); w0[4 + j] = f2b(kq[1][j]);
        w1[j] = f2b(kq[2][j]); w1[4 + j] = f2b(kq[3][j]);
      }
      *(u16x8*)(&sm.kv.Kt[hs][nb][kwo0]) = w0;
      *(u16x8*)(&sm.kv.Kt[hs][nb][kwo1]) = w1;
      #pragma unroll
      for (int jd = 0; jd < 4; ++jd) {
        const int row = vd + jd;
        u16x4 vw;
        #pragma unroll
        for (int i = 0; i < 4; ++i) vw[i] = f2b(vq[i][jd]);
        *(u16x4*)(&sm.kv.Vt[hs][nb][row * 64 + (((vkv >> 3) ^ (row & 7)) << 3) + (vkv & 7)]) = vw;
      }
      __syncthreads();
      cur = nb;
    }
  }

  l_run += __shfl_xor(l_run, 32);

  __syncthreads();
  if (half == 1) {
    #pragma unroll
    for (int r = 0; r < 16; ++r) {
      const int qrow = (r & 3) + 8 * (r >> 2) + 4 * hi;
      sm.cmb.O[32 * wv + qrow][l31]      = oacc[0][r];
      sm.cmb.O[32 * wv + qrow][32 + l31] = oacc[1][r];
    }
    if (hi == 0) { sm.cmb.m[32 * wv + l31] = m_run; sm.cmb.l[32 * wv + l31] = l_run; }
  }
  __syncthreads();
  if (half == 0) {
    const float m_b = sm.cmb.m[32 * wv + l31];
    const float l_b = sm.cmb.l[32 * wv + l31];
    const float mm = fmaxf(m_run, m_b);
    const float sa = exp2f(m_run - mm);
    const float sb = exp2f(m_b - mm);
    const float linv = 1.0f / (sa * l_run + sb * l_b);
    const float wa = sa * linv, wb = sb * linv;
    float* Ob = O + (((size_t)b * L_ + q0w) * H_ + h) * E_;
    #pragma unroll
    for (int r = 0; r < 16; ++r) {
      const int qrow = (r & 3) + 8 * (r >> 2) + 4 * hi;
      const float wa_r = __shfl(wa, qrow);
      const float wb_r = __shfl(wb, qrow);
      Ob[(size_t)qrow * HE + l31] =
          wa_r * oacc[0][r] + wb_r * sm.cmb.O[32 * wv + qrow][l31];
      Ob[(size_t)qrow * HE + 32 + l31] =
          wa_r * oacc[1][r] + wb_r * sm.cmb.O[32 * wv + qrow][32 + l31];
    }
  }
}

// --------------- ABLATION clones: write d_ws only, 3x repeat --------------
// V=0 full | V=1 no-staging | V=2 no-softmax | V=3 no-PV | V=4 no-QK
template <int V>
__global__ __launch_bounds__(512, 1) void abl(
    const float* __restrict__ Q, const float* __restrict__ K,
    const float* __restrict__ Vg, const float* __restrict__ tau,
    float* __restrict__ wsO)
{
  const int f  = blockIdx.x + 16 * (blockIdx.y + 8 * blockIdx.z);
  const int u  = f >> 5, hb = f & 31;
  const int h  = hb & 7, b = hb >> 3;
  const int qt = (u < 8) ? u : 23 - u;

  const int tid  = threadIdx.x;
  const int wave = tid >> 6, lane = tid & 63;
  const int l31 = lane & 31, hi = lane >> 5;
  const int l7 = l31 & 7;
  const int half = wave >> 2, wv = wave & 3;

  __shared__ unsigned short Kt[2][2][64 * 64];
  __shared__ unsigned short Vt[2][2][64 * 64];

  const float qscale = 0.125f * expf(tau[b]) * 1.44269504088896f;
  const int q0w = qt * 128 + wv * 32;
  const int myq = q0w + l31;
  const int dqd = 32 * wv + l31 - 64 * half;
  const bool skipw = (half == 1) && (wv < 2);

  const float* Qb = Q + (((size_t)b * L_ + myq) * H_ + h) * E_;
  bf16x8 qf[4];
  #pragma unroll
  for (int ks = 0; ks < 4; ++ks) {
    f32x4 a = *(const f32x4*)(Qb + ks * 16 + hi * 8);
    f32x4 c = *(const f32x4*)(Qb + ks * 16 + hi * 8 + 4);
    #pragma unroll
    for (int j = 0; j < 4; ++j) {
      qf[ks][j]     = (short)f2b(a[j] * qscale);
      qf[ks][4 + j] = (short)f2b(c[j] * qscale);
    }
  }

  const int hs = tid >> 8, st = tid & 255;
  const int krow = st >> 2, kcg = st & 3;
  const int vkv = (st & 15) * 4, vd = (st >> 4) * 4;
  const size_t bh = ((size_t)b * L_ * H_ + h) * E_;
  const float* Kp = K + bh + (size_t)(64 * hs + krow) * HE + kcg * 16;
  const float* Vp = Vg + bh + (size_t)(64 * hs + vkv) * HE + vd;
  const int kwo0 = krow * 64 + (((2 * kcg)     ^ (krow & 7)) << 3);
  const int kwo1 = krow * 64 + (((2 * kcg + 1) ^ (krow & 7)) << 3);

  const int nt = qt + 1;
  f32x4 kq[4], vq[4];

  for (int rep = 0; rep < 3; ++rep) {
    float m_run = -INFINITY, l_run = 0.0f;
    f32x16 oacc[2];
    #pragma unroll
    for (int nd = 0; nd < 2; ++nd)
      #pragma unroll
      for (int r = 0; r < 16; ++r) oacc[nd][r] = 0.0f;

    __syncthreads();                         // LDS reuse across reps
    #pragma unroll
    for (int i = 0; i < 4; ++i) kq[i] = *(const f32x4*)(Kp + 4 * i);
    #pragma unroll
    for (int i = 0; i < 4; ++i) vq[i] = *(const f32x4*)(Vp + (size_t)i * HE);
    {
      u16x8 w0, w1;
      #pragma unroll
      for (int j = 0; j < 4; ++j) {
        w0[j] = f2b(kq[0][j]); w0[4 + j] = f2b(kq[1][j]);
        w1[j] = f2b(kq[2][j]); w1[4 + j] = f2b(kq[3][j]);
      }
      *(u16x8*)(&Kt[hs][0][kwo0]) = w0;
      *(u16x8*)(&Kt[hs][0][kwo1]) = w1;
      #pragma unroll
      for (int jd = 0; jd < 4; ++jd) {
        const int row = vd + jd;
        u16x4 vw;
        #pragma unroll
        for (int i = 0; i < 4; ++i) vw[i] = f2b(vq[i][jd]);
        *(u16x4*)(&Vt[hs][0][row * 64 + (((vkv >> 3) ^ (row & 7)) << 3) + (vkv & 7)]) = vw;
      }
    }
    __syncthreads();
    int cur = 0;

    for (int t = 0; t < nt; ++t) {
      const bool havenext = (t + 1 < nt);
      if constexpr (V != 1) {
        if (havenext) {
          const float* Kn = Kp + (size_t)(t + 1) * 128 * HE;
          const float* Vn = Vp + (size_t)(t + 1) * 128 * HE;
          #pragma unroll
          for (int i = 0; i < 4; ++i) kq[i] = *(const f32x4*)(Kn + 4 * i);
          #pragma unroll
          for (int i = 0; i < 4; ++i) vq[i] = *(const f32x4*)(Vn + (size_t)i * HE);
        }
      }

      if (!(skipw && t == nt - 1)) {
        const unsigned short* Kl = Kt[half][cur];
        const unsigned short* Vl = Vt[half][cur];

        f32x16 sacc[2];
        if constexpr (V != 4) {              // QK phase
          #pragma unroll
          for (int mt = 0; mt < 2; ++mt)
            #pragma unroll
            for (int r = 0; r < 16; ++r) sacc[mt][r] = 0.0f;
          __builtin_amdgcn_s_setprio(1);
          #pragma unroll
          for (int ks = 0; ks < 4; ++ks) {
            #pragma unroll
            for (int mt = 0; mt < 2; ++mt) {
              bf16x8 kf = *(const bf16x8*)(Kl + (32 * mt + l31) * 64 +
                                           (((2 * ks + hi) ^ l7) << 3));
              sacc[mt] = __builtin_amdgcn_mfma_f32_32x32x16_bf16(kf, qf[ks], sacc[mt], 0, 0, 0);
            }
          }
          __builtin_amdgcn_s_setprio(0);
        } else {                             // synthetic, keeps downstream
          #pragma unroll
          for (int mt = 0; mt < 2; ++mt)
            #pragma unroll
            for (int r = 0; r < 16; ++r)
              sacc[mt][r] = 0.001f * (float)(r + 16 * mt + t + lane);
        }

        if (t == nt - 1) {
          #pragma unroll
          for (int mt = 0; mt < 2; ++mt)
            #pragma unroll
            for (int r = 0; r < 16; ++r) {
              const int kvl = 32 * mt + (r & 3) + 8 * (r >> 2) + 4 * hi;
              if (kvl > dqd) sacc[mt][r] = -3.0e38f;
            }
        }

        if constexpr (V != 2) {              // softmax phase
          float p0 = sacc[0][0], p1 = sacc[0][1], p2 = sacc[0][2], p3 = sacc[0][3];
          #pragma unroll
          for (int mt = 0; mt < 2; ++mt)
            #pragma unroll
            for (int r = (mt == 0 ? 4 : 0); r < 16; r += 4) {
              p0 = fmaxf(p0, sacc[mt][r]);
              p1 = fmaxf(p1, sacc[mt][r + 1]);
              p2 = fmaxf(p2, sacc[mt][r + 2]);
              p3 = fmaxf(p3, sacc[mt][r + 3]);
            }
          float mx = fmaxf(fmaxf(p0, p1), fmaxf(p2, p3));
          mx = fmaxf(mx, __shfl_xor(mx, 32));
          if (!__all(mx - m_run <= 8.0f)) {
            const float mnew = fmaxf(m_run, mx);
            const float corr = exp2f(m_run - mnew);
            m_run = mnew;
            l_run *= corr;
            #pragma unroll
            for (int r = 0; r < 16; ++r) {
              const int qrow = (r & 3) + 8 * (r >> 2) + 4 * hi;
              const float cr = __shfl(corr, qrow);
              oacc[0][r] *= cr;
              oacc[1][r] *= cr;
            }
          }
          float s0 = 0.f, s1 = 0.f, s2 = 0.f, s3 = 0.f;
          #pragma unroll
          for (int mt = 0; mt < 2; ++mt)
            #pragma unroll
            for (int r = 0; r < 16; r += 4) {
              float e0 = exp2f(sacc[mt][r]     - m_run);
              float e1 = exp2f(sacc[mt][r + 1] - m_run);
              float e2 = exp2f(sacc[mt][r + 2] - m_run);
              float e3 = exp2f(sacc[mt][r + 3] - m_run);
              sacc[mt][r] = e0; sacc[mt][r + 1] = e1;
              sacc[mt][r + 2] = e2; sacc[mt][r + 3] = e3;
              s0 += e0; s1 += e1; s2 += e2; s3 += e3;
            }
          l_run += (s0 + s1) + (s2 + s3);
        } else {
          l_run += sacc[0][0] + sacc[1][15]; // keep dependence
        }

        if constexpr (V != 3) {              // PV phase
          unsigned pk[2][8];
          #pragma unroll
          for (int mt = 0; mt < 2; ++mt)
            #pragma unroll
            for (int i = 0; i < 8; ++i)
              pk[mt][i] = cvtpk(sacc[mt][2 * i], sacc[mt][2 * i + 1]);
          __builtin_amdgcn_s_setprio(1);
          #pragma unroll
          for (int ks = 0; ks < 4; ++ks) {
            const int c = ks & 1, mtx = ks >> 1;
            unsigned a  = pk[mtx][4 * c];
            unsigned y  = pk[mtx][4 * c + 2];
            unsigned a2 = pk[mtx][4 * c + 1];
            unsigned y2 = pk[mtx][4 * c + 3];
            pl32swap(a, y);
            pl32swap(a2, y2);
            union { unsigned w[4]; bf16x8 v; } pu;
            pu.w[0] = a; pu.w[1] = a2; pu.w[2] = y; pu.w[3] = y2;
            #pragma unroll
            for (int nd = 0; nd < 2; ++nd) {
              bf16x8 vf = *(const bf16x8*)(Vl + (32 * nd + l31) * 64 +
                                           (((2 * ks + hi) ^ l7) << 3));
              oacc[nd] = __builtin_amdgcn_mfma_f32_32x32x16_bf16(pu.v, vf, oacc[nd], 0, 0, 0);
            }
          }
          __builtin_amdgcn_s_setprio(0);
        }
      }

      if (havenext) {
        if constexpr (V != 1) {
          const int nb = cur ^ 1;
          u16x8 w0, w1;
          #pragma unroll
          for (int j = 0; j < 4; ++j) {
            w0[j] = f2b(kq[0][j]); w0[4 + j] = f2b(kq[1][j]);
            w1[j] = f2b(kq[2][j]); w1[4 + j] = f2b(kq[3][j]);
          }
          *(u16x8*)(&Kt[hs][nb][kwo0]) = w0;
          *(u16x8*)(&Kt[hs][nb][kwo1]) = w1;
          #pragma unroll
          for (int jd = 0; jd < 4; ++jd) {
            const int row = vd + jd;
            u16x4 vw;
            #pragma unroll
            for (int i = 0; i < 4; ++i) vw[i] = f2b(vq[i][jd]);
            *(u16x4*)(&Vt[hs][nb][row * 64 + (((vkv >> 3) ^ (row & 7)) << 3) + (vkv & 7)]) = vw;
          }
          __syncthreads();
          cur = nb;
        } else {
          __syncthreads();                   // keep barrier cadence
        }
      }
    }

    // keep everything live: disjoint d_ws slots (col = 32*half + l31)
    float* Ob = wsO + (((size_t)b * L_ + q0w) * H_ + h) * E_;
    #pragma unroll
    for (int r = 0; r < 16; ++r) {
      const int qrow = (r & 3) + 8 * (r >> 2) + 4 * hi;
      Ob[(size_t)qrow * HE + 32 * half + l31] = oacc[0][r] + oacc[1][r] + l_run;
    }
  }
}

extern "C" void kernel_launch(void* const* d_in, const int* in_sizes, int n_in,
                              void* d_out, int out_size, void* d_ws, size_t ws_size,
                              hipStream_t stream) {
  (void)in_sizes; (void)n_in; (void)out_size; (void)ws_size;
  const float* Q   = (const float*)d_in[0];
  const float* K   = (const float*)d_in[1];
  const float* V   = (const float*)d_in[2];
  // d_in[3] = attn_mask: ignored, causality applied analytically.
  const float* tau = (const float*)d_in[4];
  float* O = (float*)d_out;
  float* wsO = (float*)d_ws;                 // 16.8 MB scratch for ablation

  dim3 grid(16, 8, 4), block(512);
  hipLaunchKernelGGL(attn_fwd, grid, block, 0, stream, Q, K, V, tau, O);
  hipLaunchKernelGGL((abl<0>), grid, block, 0, stream, Q, K, V, tau, wsO);
  hipLaunchKernelGGL((abl<1>), grid, block, 0, stream, Q, K, V, tau, wsO);
  hipLaunchKernelGGL((abl<2>), grid, block, 0, stream, Q, K, V, tau, wsO);
  hipLaunchKernelGGL((abl<3>), grid, block, 0, stream, Q, K, V, tau, wsO);
  hipLaunchKernelGGL((abl<4>), grid, block, 0, stream, Q, K, V, tau, wsO);
}

// Round 18
// 58.772 us; speedup vs baseline: 10.4996x; 10.4996x over previous
//
#include <hip/hip_runtime.h>
#include <hip/hip_bf16.h>
#include <math.h>

#define B_ 4
#define L_ 2048
#define H_ 8
#define E_ 64
#define HE 512   // H_*E_ : float stride between consecutive seq positions

typedef short bf16x8 __attribute__((ext_vector_type(8)));
typedef float f32x4 __attribute__((ext_vector_type(4)));
typedef float f32x16 __attribute__((ext_vector_type(16)));
typedef unsigned short u16x4 __attribute__((ext_vector_type(4)));
typedef unsigned short u16x8 __attribute__((ext_vector_type(8)));

__device__ __forceinline__ unsigned short f2b(float f) {
  return __builtin_bit_cast(unsigned short, (__hip_bfloat16)f);
}
__device__ __forceinline__ unsigned cvtpk(float lo, float hi) {
  unsigned r;
  asm("v_cvt_pk_bf16_f32 %0, %1, %2" : "=v"(r) : "v"(lo), "v"(hi));
  return r;
}
// T12 pair-swap: verified ONLY with two distinct live values (PV path).
__device__ __forceinline__ void pl32swap(unsigned &a, unsigned &b) {
  asm volatile("v_permlane32_swap_b32 %0, %1" : "+v"(a), "+v"(b));
}

// ---- prep: K,V f32 -> bf16 in d_ws, PRE-SWIZZLED to the exact byte layout
// the main kernel's LDS tiles use. Reuses R16's verified staging code, then
// linearly dumps LDS -> ws. Main staging becomes a pure linear bf16 copy.
__global__ __launch_bounds__(256) void prep(
    const float* __restrict__ K, const float* __restrict__ V,
    unsigned short* __restrict__ Kws, unsigned short* __restrict__ Vws)
{
  const int tile = blockIdx.x;                 // 64-kv tile 0..31
  const int hb   = blockIdx.y;                 // 0..31
  const int h = hb & 7, b = hb >> 3;
  const int st = threadIdx.x;

  __shared__ unsigned short lK[64 * 64];
  __shared__ unsigned short lV[64 * 64];

  const int krow = st >> 2, kcg = st & 3;
  const int vkv = (st & 15) * 4, vd = (st >> 4) * 4;
  const size_t bh = ((size_t)b * L_ * H_ + h) * E_;
  const float* Kp = K + bh + (size_t)(64 * tile + krow) * HE + kcg * 16;
  const float* Vp = V + bh + (size_t)(64 * tile + vkv) * HE + vd;
  const int kwo0 = krow * 64 + (((2 * kcg)     ^ (krow & 7)) << 3);
  const int kwo1 = krow * 64 + (((2 * kcg + 1) ^ (krow & 7)) << 3);

  f32x4 kq[4], vq[4];
  #pragma unroll
  for (int i = 0; i < 4; ++i) kq[i] = *(const f32x4*)(Kp + 4 * i);
  #pragma unroll
  for (int i = 0; i < 4; ++i) vq[i] = *(const f32x4*)(Vp + (size_t)i * HE);

  u16x8 w0, w1;
  #pragma unroll
  for (int j = 0; j < 4; ++j) {
    w0[j] = f2b(kq[0][j]); w0[4 + j] = f2b(kq[1][j]);
    w1[j] = f2b(kq[2][j]); w1[4 + j] = f2b(kq[3][j]);
  }
  *(u16x8*)(&lK[kwo0]) = w0;
  *(u16x8*)(&lK[kwo1]) = w1;
  #pragma unroll
  for (int jd = 0; jd < 4; ++jd) {
    const int row = vd + jd;
    u16x4 vw;
    #pragma unroll
    for (int i = 0; i < 4; ++i) vw[i] = f2b(vq[i][jd]);
    *(u16x4*)(&lV[row * 64 + (((vkv >> 3) ^ (row & 7)) << 3) + (vkv & 7)]) = vw;
  }
  __syncthreads();

  // linear dump: ws layout == LDS layout (granule g = 16B at offset g*8)
  unsigned short* Kd = Kws + ((size_t)hb * 32 + tile) * 4096;
  unsigned short* Vd = Vws + ((size_t)hb * 32 + tile) * 4096;
  *(u16x8*)(Kd + st * 8)        = *(const u16x8*)(lK + st * 8);
  *(u16x8*)(Kd + 2048 + st * 8) = *(const u16x8*)(lK + 2048 + st * 8);
  *(u16x8*)(Vd + st * 8)        = *(const u16x8*)(lV + st * 8);
  *(u16x8*)(Vd + 2048 + st * 8) = *(const u16x8*)(lV + 2048 + st * 8);
}

// ---- main: R16 (verified) with staging replaced by pure bf16 linear copy
// from the prep'd ws (no f32 loads, no converts, no transpose scatter).
__global__ __launch_bounds__(512, 1) void attn_fwd(
    const float* __restrict__ Q, const unsigned short* __restrict__ Kws,
    const unsigned short* __restrict__ Vws, const float* __restrict__ tau,
    float* __restrict__ O)
{
  const int f  = blockIdx.x + 16 * (blockIdx.y + 8 * blockIdx.z);
  const int u  = f >> 5, hb = f & 31;
  const int h  = hb & 7, b = hb >> 3;
  const int qt = (u < 8) ? u : 23 - u;

  const int tid  = threadIdx.x;
  const int wave = tid >> 6, lane = tid & 63;
  const int l31 = lane & 31, hi = lane >> 5;
  const int l7 = l31 & 7;
  const int half = wave >> 2, wv = wave & 3;

  __shared__ union {
    struct { unsigned short Kt[2][2][64 * 64];
             unsigned short Vt[2][2][64 * 64]; } kv;
    struct { float O[128][64]; float m[128]; float l[128]; } cmb;
  } sm;

  const float qscale = 0.125f * expf(tau[b]) * 1.44269504088896f;
  const int q0w = qt * 128 + wv * 32;
  const int myq = q0w + l31;
  const int dqd = 32 * wv + l31 - 64 * half;
  const bool skipw = (half == 1) && (wv < 2);

  const float* Qb = Q + (((size_t)b * L_ + myq) * H_ + h) * E_;
  bf16x8 qf[4];
  #pragma unroll
  for (int ks = 0; ks < 4; ++ks) {
    f32x4 a = *(const f32x4*)(Qb + ks * 16 + hi * 8);
    f32x4 c = *(const f32x4*)(Qb + ks * 16 + hi * 8 + 4);
    #pragma unroll
    for (int j = 0; j < 4; ++j) {
      qf[ks][j]     = (short)f2b(a[j] * qscale);
      qf[ks][4 + j] = (short)f2b(c[j] * qscale);
    }
  }

  float m_run = -INFINITY, l_run = 0.0f;       // l_run: per-lane partial
  f32x16 oacc[2];
  #pragma unroll
  for (int nd = 0; nd < 2; ++nd)
    #pragma unroll
    for (int r = 0; r < 16; ++r) oacc[nd][r] = 0.0f;

  // staging: threads <256 stage half 0 (even tiles), >=256 half 1 (odd)
  const int hs = tid >> 8, st = tid & 255;
  const unsigned short* Kb = Kws + (size_t)hb * 32 * 4096;
  const unsigned short* Vb = Vws + (size_t)hb * 32 * 4096;

  const int nt = qt + 1;   // iterations; half h_ sees tiles 2i + h_

  u16x8 kA, kB, vA, vB;
  auto load_tile = [&](int t64) {              // 64-kv tile index in ws
    const unsigned short* Ks = Kb + (size_t)t64 * 4096;
    const unsigned short* Vs = Vb + (size_t)t64 * 4096;
    kA = *(const u16x8*)(Ks + st * 8);
    kB = *(const u16x8*)(Ks + 2048 + st * 8);
    vA = *(const u16x8*)(Vs + st * 8);
    vB = *(const u16x8*)(Vs + 2048 + st * 8);
  };
  auto stage_write = [&](int nb) {             // pure linear b128 writes
    *(u16x8*)(&sm.kv.Kt[hs][nb][st * 8])        = kA;
    *(u16x8*)(&sm.kv.Kt[hs][nb][2048 + st * 8]) = kB;
    *(u16x8*)(&sm.kv.Vt[hs][nb][st * 8])        = vA;
    *(u16x8*)(&sm.kv.Vt[hs][nb][2048 + st * 8]) = vB;
  };

  load_tile(hs);
  stage_write(0);
  __syncthreads();
  int cur = 0;

  for (int t = 0; t < nt; ++t) {
    const bool havenext = (t + 1 < nt);
    if (havenext) load_tile(2 * (t + 1) + hs); // T14: issue loads early

    if (!(skipw && t == nt - 1)) {
      const unsigned short* Kl = sm.kv.Kt[half][cur];
      const unsigned short* Vl = sm.kv.Vt[half][cur];

      // ---- S^T = K Q^T : 8 MFMAs ----
      f32x16 sacc[2];
      #pragma unroll
      for (int mt = 0; mt < 2; ++mt)
        #pragma unroll
        for (int r = 0; r < 16; ++r) sacc[mt][r] = 0.0f;
      __builtin_amdgcn_s_setprio(1);
      #pragma unroll
      for (int ks = 0; ks < 4; ++ks) {
        #pragma unroll
        for (int mt = 0; mt < 2; ++mt) {
          bf16x8 kf = *(const bf16x8*)(Kl + (32 * mt + l31) * 64 +
                                       (((2 * ks + hi) ^ l7) << 3));
          sacc[mt] = __builtin_amdgcn_mfma_f32_32x32x16_bf16(kf, qf[ks], sacc[mt], 0, 0, 0);
        }
      }
      __builtin_amdgcn_s_setprio(0);

      // ---- causal mask (diagonal iteration only) ----
      if (t == nt - 1) {
        #pragma unroll
        for (int mt = 0; mt < 2; ++mt)
          #pragma unroll
          for (int r = 0; r < 16; ++r) {
            const int kvl = 32 * mt + (r & 3) + 8 * (r >> 2) + 4 * hi;
            if (kvl > dqd) sacc[mt][r] = -3.0e38f;
          }
      }

      // ---- online softmax: max tree + defer-max (T13) ----
      float p0 = sacc[0][0], p1 = sacc[0][1], p2 = sacc[0][2], p3 = sacc[0][3];
      #pragma unroll
      for (int mt = 0; mt < 2; ++mt)
        #pragma unroll
        for (int r = (mt == 0 ? 4 : 0); r < 16; r += 4) {
          p0 = fmaxf(p0, sacc[mt][r]);
          p1 = fmaxf(p1, sacc[mt][r + 1]);
          p2 = fmaxf(p2, sacc[mt][r + 2]);
          p3 = fmaxf(p3, sacc[mt][r + 3]);
        }
      float mx = fmaxf(fmaxf(p0, p1), fmaxf(p2, p3));
      mx = fmaxf(mx, __shfl_xor(mx, 32));      // proven cross-half reduce

      if (!__all(mx - m_run <= 8.0f)) {        // rescale needed (rare)
        const float mnew = fmaxf(m_run, mx);
        const float corr = exp2f(m_run - mnew);
        m_run = mnew;
        l_run *= corr;
        #pragma unroll
        for (int r = 0; r < 16; ++r) {
          const int qrow = (r & 3) + 8 * (r >> 2) + 4 * hi;
          const float cr = __shfl(corr, qrow);
          oacc[0][r] *= cr;
          oacc[1][r] *= cr;
        }
      }

      float s0 = 0.f, s1 = 0.f, s2 = 0.f, s3 = 0.f;
      #pragma unroll
      for (int mt = 0; mt < 2; ++mt)
        #pragma unroll
        for (int r = 0; r < 16; r += 4) {
          float e0 = exp2f(sacc[mt][r]     - m_run);
          float e1 = exp2f(sacc[mt][r + 1] - m_run);
          float e2 = exp2f(sacc[mt][r + 2] - m_run);
          float e3 = exp2f(sacc[mt][r + 3] - m_run);
          sacc[mt][r] = e0; sacc[mt][r + 1] = e1;
          sacc[mt][r + 2] = e2; sacc[mt][r + 3] = e3;
          s0 += e0; s1 += e1; s2 += e2; s3 += e3;
        }
      l_run += (s0 + s1) + (s2 + s3);          // deferred: no cross-lane

      // ---- P -> bf16 packed words (T12 step 1) ----
      unsigned pk[2][8];
      #pragma unroll
      for (int mt = 0; mt < 2; ++mt)
        #pragma unroll
        for (int i = 0; i < 8; ++i)
          pk[mt][i] = cvtpk(sacc[mt][2 * i], sacc[mt][2 * i + 1]);

      // ---- O += P V : 8 MFMAs; pf via permlane32_swap (T12 step 2) ----
      __builtin_amdgcn_s_setprio(1);
      #pragma unroll
      for (int ks = 0; ks < 4; ++ks) {
        const int c = ks & 1, mtx = ks >> 1;
        unsigned a  = pk[mtx][4 * c];
        unsigned y  = pk[mtx][4 * c + 2];
        unsigned a2 = pk[mtx][4 * c + 1];
        unsigned y2 = pk[mtx][4 * c + 3];
        pl32swap(a, y);
        pl32swap(a2, y2);
        union { unsigned w[4]; bf16x8 v; } pu;
        pu.w[0] = a; pu.w[1] = a2; pu.w[2] = y; pu.w[3] = y2;
        #pragma unroll
        for (int nd = 0; nd < 2; ++nd) {
          bf16x8 vf = *(const bf16x8*)(Vl + (32 * nd + l31) * 64 +
                                       (((2 * ks + hi) ^ l7) << 3));
          oacc[nd] = __builtin_amdgcn_mfma_f32_32x32x16_bf16(pu.v, vf, oacc[nd], 0, 0, 0);
        }
      }
      __builtin_amdgcn_s_setprio(0);
    }

    if (havenext) {
      stage_write(cur ^ 1);
      __syncthreads();
      cur ^= 1;
    }
  }

  // ---- epilogue: reduce l partial once, then merge the two kv-halves ----
  l_run += __shfl_xor(l_run, 32);

  __syncthreads();
  if (half == 1) {
    #pragma unroll
    for (int r = 0; r < 16; ++r) {
      const int qrow = (r & 3) + 8 * (r >> 2) + 4 * hi;
      sm.cmb.O[32 * wv + qrow][l31]      = oacc[0][r];
      sm.cmb.O[32 * wv + qrow][32 + l31] = oacc[1][r];
    }
    if (hi == 0) { sm.cmb.m[32 * wv + l31] = m_run; sm.cmb.l[32 * wv + l31] = l_run; }
  }
  __syncthreads();
  if (half == 0) {
    const float m_b = sm.cmb.m[32 * wv + l31];
    const float l_b = sm.cmb.l[32 * wv + l31];
    const float mm = fmaxf(m_run, m_b);
    const float sa = exp2f(m_run - mm);
    const float sb = exp2f(m_b - mm);          // m_b=-inf (empty half) -> 0
    const float linv = 1.0f / (sa * l_run + sb * l_b);
    const float wa = sa * linv, wb = sb * linv;
    float* Ob = O + (((size_t)b * L_ + q0w) * H_ + h) * E_;
    #pragma unroll
    for (int r = 0; r < 16; ++r) {
      const int qrow = (r & 3) + 8 * (r >> 2) + 4 * hi;
      const float wa_r = __shfl(wa, qrow);
      const float wb_r = __shfl(wb, qrow);
      Ob[(size_t)qrow * HE + l31] =
          wa_r * oacc[0][r] + wb_r * sm.cmb.O[32 * wv + qrow][l31];
      Ob[(size_t)qrow * HE + 32 + l31] =
          wa_r * oacc[1][r] + wb_r * sm.cmb.O[32 * wv + qrow][32 + l31];
    }
  }
}

extern "C" void kernel_launch(void* const* d_in, const int* in_sizes, int n_in,
                              void* d_out, int out_size, void* d_ws, size_t ws_size,
                              hipStream_t stream) {
  (void)in_sizes; (void)n_in; (void)out_size; (void)ws_size;
  const float* Q   = (const float*)d_in[0];
  const float* K   = (const float*)d_in[1];
  const float* V   = (const float*)d_in[2];
  // d_in[3] = attn_mask: ignored, causality applied analytically.
  const float* tau = (const float*)d_in[4];
  float* O = (float*)d_out;

  unsigned short* Kws = (unsigned short*)d_ws;          // 32*32*4096*2B
  unsigned short* Vws = Kws + (size_t)32 * 32 * 4096;   // = 8.39 MB each

  hipLaunchKernelGGL(prep, dim3(32, 32), dim3(256), 0, stream, K, V, Kws, Vws);
  dim3 grid(16, 8, 4), block(512);
  hipLaunchKernelGGL(attn_fwd, grid, block, 0, stream, Q, Kws, Vws, tau, O);
}